// Round 11
// baseline (441.647 us; speedup 1.0000x reference)
//
#include <hip/hip_runtime.h>
#include <math.h>

#define BB 1024        // batch
#define DD 512         // feature dim
#define CC 50000       // classes
#define KMAX 1024      // max compacted classes
#define HSZ 2048       // hash size
#define PLCAP 64       // per-row positive-list capacity (expected ~2)
#define NB 1024        // 4 blocks/CU (capacity 8) -> co-residency with 2x margin
#define SCALE_F 16.0f
#define EPS_F 0.1f

typedef __bf16 bf16_t;
typedef bf16_t bf16x2 __attribute__((ext_vector_type(2)));
typedef bf16_t bf16x8 __attribute__((ext_vector_type(8)));
typedef float f32x4 __attribute__((ext_vector_type(4)));

__device__ __forceinline__ unsigned hashc(int c) {
    return ((unsigned)c * 2654435761u) >> 21;   // 0..2047
}

__device__ __forceinline__ void hash_insert(int* gkey, int* gval, int* kctr,
                                            int* sc, int c) {
    unsigned h = hashc(c);
    for (int p = 0; p < HSZ; ++p) {
        int old = atomicCAS(&gkey[h], -1, c);
        if (old == -1) {                  // owner: allocate rank
            int r = atomicAdd(kctr, 1);
            gval[h] = r;
            if (r < KMAX) sc[r] = c;
            return;
        }
        if (old == c) return;
        h = (h + 1) & (HSZ - 1);
    }
}

// grid-wide barrier (R9-proven): arrive counter + flag spin, agent scope.
// Deadlock-safe: NB=1024 = half the guaranteed co-resident capacity.
__device__ __forceinline__ void gsync(int* ctr, int* flag, int idx) {
    __syncthreads();
    if (threadIdx.x == 0) {
        __threadfence();
        int arrived = __hip_atomic_fetch_add(&ctr[idx], 1, __ATOMIC_ACQ_REL,
                                             __HIP_MEMORY_SCOPE_AGENT);
        if (arrived == NB - 1) {
            __hip_atomic_store(&flag[idx], 1, __ATOMIC_RELEASE,
                               __HIP_MEMORY_SCOPE_AGENT);
        } else {
            while (__hip_atomic_load(&flag[idx], __ATOMIC_ACQUIRE,
                                     __HIP_MEMORY_SCOPE_AGENT) == 0)
                __builtin_amdgcn_s_sleep(8);
        }
    }
    __syncthreads();
}

// 32x32 MFMA tile (bf16 3-term split on raw values, fp32 accum); epilogue
// scales by 16*rnA*rnB, stores simc, accumulates seAcc[row] += sum exp(sim).
__device__ __forceinline__ void gemm_tile(int t, int Kv,
        const bf16_t* __restrict__ AH, const bf16_t* __restrict__ AL,
        const bf16_t* __restrict__ BH, const bf16_t* __restrict__ BL,
        const float* __restrict__ rnA, const float* __restrict__ rnB,
        float* __restrict__ simc, float* __restrict__ seAcc, float* sem) {
    int tid = threadIdx.x;
    if (tid < 32) sem[tid] = 0.0f;
    __syncthreads();
    int wave = tid >> 6, lane = tid & 63;
    int by = t >> 5, bx = t & 31;
    int b0 = by * 32 + (wave >> 1) * 16;
    int k0 = bx * 32 + (wave & 1) * 16;
    int frow = lane & 15;
    int koff = (lane >> 4) * 8;
    const bf16_t* pAh = AH + (size_t)(b0 + frow) * DD + koff;
    const bf16_t* pAl = AL + (size_t)(b0 + frow) * DD + koff;
    const bf16_t* pBh = BH + (size_t)(k0 + frow) * DD + koff;
    const bf16_t* pBl = BL + (size_t)(k0 + frow) * DD + koff;
    f32x4 acc = {};
    #pragma unroll 2
    for (int dk = 0; dk < DD; dk += 32) {
        bf16x8 ah = *(const bf16x8*)(pAh + dk);
        bf16x8 al = *(const bf16x8*)(pAl + dk);
        bf16x8 bh = *(const bf16x8*)(pBh + dk);
        bf16x8 bl = *(const bf16x8*)(pBl + dk);
        acc = __builtin_amdgcn_mfma_f32_16x16x32_bf16(ah, bh, acc, 0, 0, 0);
        acc = __builtin_amdgcn_mfma_f32_16x16x32_bf16(ah, bl, acc, 0, 0, 0);
        acc = __builtin_amdgcn_mfma_f32_16x16x32_bf16(al, bh, acc, 0, 0, 0);
    }
    // C/D layout: col = lane&15, row = (lane>>4)*4 + reg
    int r4 = (lane >> 4) * 4;
    int col = k0 + (lane & 15);
    float rb = rnB[col];
    #pragma unroll
    for (int r = 0; r < 4; ++r) {
        int row = b0 + r4 + r;
        float s = acc[r] * SCALE_F * rnA[row] * rb;
        simc[(size_t)row * KMAX + col] = s;
        float e = (col < Kv) ? expf(s) : 0.0f;
        #pragma unroll
        for (int o = 1; o < 16; o <<= 1) e += __shfl_xor(e, o, 16);
        if ((lane & 15) == 0) atomicAdd(&sem[(wave >> 1) * 16 + r4 + r], e);
    }
    __syncthreads();
    if (tid < 32) atomicAdd(&seAcc[by * 32 + tid], sem[tid]);
    __syncthreads();
}

// sparse positive extraction: pm row is L3-resident; ~2 nonzeros survive.
__device__ __forceinline__ void gather_row(const float* __restrict__ pm, int b,
                                           const int* __restrict__ sc, int Kv,
                                           int* pcnt, int* pkidx, float* pval) {
    const float* __restrict__ row = pm + (size_t)b * CC;
    int tid = threadIdx.x;
    #pragma unroll
    for (int j = 0; j < 4; ++j) {
        int k = tid + j * 256;
        if (k < Kv) {
            float v = row[sc[k]];
            if (v != 0.0f) {
                int slot = atomicAdd(&pcnt[b], 1);
                if (slot < PLCAP) {
                    pkidx[b * PLCAP + slot] = k;
                    pval[b * PLCAP + slot] = v;
                }
            }
        }
    }
}

// LDS layout (union across phases), 4160 ints = 16.6 KB:
//  P2-class: members = smem[0..1024), red = smem[2048..2304), mcount = smem[3072]
//  P3-gemm:  sem = smem[0..32)
//  P4:       hk = smem[0..2048), hv = smem[2048..4096); then red2 = smem[0..256)
__global__ __launch_bounds__(256, 4) void k_fused(
        const float* __restrict__ inputs, const float* __restrict__ pm,
        const float* __restrict__ fmem, const int* __restrict__ lmem,
        const int* __restrict__ targets,
        int* gkey, int* gval, int* sc, int* kctr,
        int* pcnt, int* pkidx, float* pval, float* seAcc,
        float* rnA, float* rnB,
        bf16_t* AH, bf16_t* AL, bf16_t* BH, bf16_t* BL,
        float* simc, int* ctr, int* flag, float* outp)
{
    __shared__ int smem[4160];
    const int bid = blockIdx.x, tid = threadIdx.x;

    // ---------------- P1: hash inserts (targets + lmem) ----------------
    if (bid < 4) {
        hash_insert(gkey, gval, kctr, sc, targets[bid * 256 + tid]);
    } else if (bid < 200) {
        int c = (bid - 4) * 256 + tid;
        if (c < CC && lmem[c] != -1) hash_insert(gkey, gval, kctr, sc, c);
    }
    gsync(ctr, flag, 0);

    int Kv = *kctr; if (Kv > KMAX) Kv = KMAX;
    int d0 = tid * 2;
    float* red = (float*)(smem + 2048);

    // ---------------- P2: row split + class sum (1 each per block) ------
    {
        int b = bid;
        float a0 = inputs[b * DD + d0];
        float a1 = inputs[b * DD + d0 + 1];
        red[tid] = a0 * a0 + a1 * a1;
        __syncthreads();
        for (int s = 128; s > 0; s >>= 1) {
            if (tid < s) red[tid] += red[tid + s];
            __syncthreads();
        }
        if (tid == 0) rnA[b] = 1.0f / fmaxf(sqrtf(red[0]), 1e-12f);
        bf16_t h0 = (bf16_t)a0, h1 = (bf16_t)a1;
        bf16x2 ph; ph[0] = h0; ph[1] = h1;
        bf16x2 pl; pl[0] = (bf16_t)(a0 - (float)h0); pl[1] = (bf16_t)(a1 - (float)h1);
        *(bf16x2*)(AH + b * DD + d0) = ph;
        *(bf16x2*)(AL + b * DD + d0) = pl;
        __syncthreads();

        int k = bid;
        if (k < Kv) {
            int c = sc[k];
            int* members = smem;
            int* mcountp = smem + 3072;
            if (tid == 0) *mcountp = 0;
            __syncthreads();
            int4 t4 = *(const int4*)(targets + tid * 4);
            if (t4.x == c) { int s = atomicAdd(mcountp, 1); members[s] = tid * 4 + 0; }
            if (t4.y == c) { int s = atomicAdd(mcountp, 1); members[s] = tid * 4 + 1; }
            if (t4.z == c) { int s = atomicAdd(mcountp, 1); members[s] = tid * 4 + 2; }
            if (t4.w == c) { int s = atomicAdd(mcountp, 1); members[s] = tid * 4 + 3; }
            __syncthreads();
            int mc = *mcountp;
            float b0v = 0.0f, b1v = 0.0f;
            if (mc == 0) {                 // lmem-only class: memory row
                b0v = fmem[(size_t)c * DD + d0];
                b1v = fmem[(size_t)c * DD + d0 + 1];
            } else {                       // sum member rows (/count cancels)
                for (int i = 0; i < mc; ++i) {
                    int bb = members[i];
                    b0v += inputs[bb * DD + d0];
                    b1v += inputs[bb * DD + d0 + 1];
                }
            }
            red[tid] = b0v * b0v + b1v * b1v;
            __syncthreads();
            for (int s = 128; s > 0; s >>= 1) {
                if (tid < s) red[tid] += red[tid + s];
                __syncthreads();
            }
            if (tid == 0) rnB[k] = 1.0f / fmaxf(sqrtf(red[0]), 1e-12f);
            bf16_t g0 = (bf16_t)b0v, g1 = (bf16_t)b1v;
            bf16x2 ph2; ph2[0] = g0; ph2[1] = g1;
            bf16x2 pl2; pl2[0] = (bf16_t)(b0v - (float)g0); pl2[1] = (bf16_t)(b1v - (float)g1);
            *(bf16x2*)(BH + k * DD + d0) = ph2;
            *(bf16x2*)(BL + k * DD + d0) = pl2;
        } else {                           // zero-pad so GEMM reads zeros
            bf16x2 z; z[0] = (bf16_t)0.0f; z[1] = (bf16_t)0.0f;
            *(bf16x2*)(BH + k * DD + d0) = z;
            *(bf16x2*)(BL + k * DD + d0) = z;
            if (tid == 0) rnB[k] = 0.0f;
        }
    }
    gsync(ctr, flag, 1);

    // ---------------- P3: gather (L3) ∥ GEMM tile, parity-staggered -----
    {
        float* sem = (float*)smem;
        if (bid & 1) {
            gemm_tile(bid, Kv, AH, AL, BH, BL, rnA, rnB, simc, seAcc, sem);
            gather_row(pm, bid, sc, Kv, pcnt, pkidx, pval);
        } else {
            gather_row(pm, bid, sc, Kv, pcnt, pkidx, pval);
            gemm_tile(bid, Kv, AH, AL, BH, BL, rnA, rnB, simc, seAcc, sem);
        }
    }
    gsync(ctr, flag, 2);

    // ---------------- P4: loss tail (block 0) ---------------------------
    if (bid != 0) return;
    int* hk = smem;
    int* hv = smem + 2048;
    for (int i = tid; i < HSZ; i += 256) { hk[i] = gkey[i]; hv[i] = gval[i]; }
    __syncthreads();
    float accl = 0.0f;
    for (int j = 0; j < 4; ++j) {
        int b = tid + j * 256;
        int c = targets[b];
        unsigned h = hashc(c);
        for (int p = 0; p < HSZ && hk[h] != c; ++p) h = (h + 1) & (HSZ - 1);
        int rt = hv[h];
        const float* __restrict__ srow = simc + (size_t)b * KMAX;
        float st = srow[rt];
        int cnt = pcnt[b]; if (cnt > PLCAP) cnt = PLCAP;
        float sp = 0.0f, spe = 0.0f;
        for (int i = 0; i < cnt; ++i) {
            float v = pval[b * PLCAP + i];
            sp += v;
            spe += v * expf(srow[pkidx[b * PLCAP + i]]);
        }
        float sneg = seAcc[b] - spe;       // sum (1-pm)*exp over valid
        float lb = (1.0f - EPS_F) * (st - logf(sneg + expf(st)));
        float inv = EPS_F / sp;
        for (int i = 0; i < cnt; ++i) {
            float s = srow[pkidx[b * PLCAP + i]];
            lb += inv * pval[b * PLCAP + i] * (s - logf(sneg + expf(s)));
        }
        accl += lb;
    }
    __syncthreads();                       // done with hash before smem reuse
    float* red2 = (float*)smem;
    red2[tid] = accl;
    __syncthreads();
    for (int s = 128; s > 0; s >>= 1) {
        if (tid < s) red2[tid] += red2[tid + s];
        __syncthreads();
    }
    if (tid == 0) outp[0] = -red2[0] * (1.0f / BB);
}

extern "C" void kernel_launch(void* const* d_in, const int* in_sizes, int n_in,
                              void* d_out, int out_size, void* d_ws, size_t ws_size,
                              hipStream_t stream) {
    const float* inputs  = (const float*)d_in[0];
    const float* pmask   = (const float*)d_in[1];
    const float* fmem    = (const float*)d_in[2];
    const int*   lmem    = (const int*)d_in[3];
    const int*   targets = (const int*)d_in[4];
    float* outp = (float*)d_out;

    char* ws = (char*)d_ws;
    size_t off = 0;
    auto alloc = [&](size_t bytes) -> void* {
        void* p = ws + off;
        off = (off + bytes + 255) & ~(size_t)255;
        return p;
    };
    // zero region (one memset): kctr/ctr/flag | pcnt | seAcc
    int*    zreg    = (int*)alloc(256 + BB * sizeof(int) + BB * sizeof(float));
    int*    kctr    = zreg;
    int*    ctr     = zreg + 8;
    int*    flag    = zreg + 16;
    int*    pcnt    = zreg + 64;                 // byte offset 256
    float*  seAcc   = (float*)(zreg + 64 + BB);
    // hash region (one 0xFF memset): gkey | gval
    int*    gkey    = (int*)alloc(2 * HSZ * sizeof(int));
    int*    gval    = gkey + HSZ;

    int*    sc      = (int*)alloc(KMAX * sizeof(int));
    int*    pkidx   = (int*)alloc((size_t)BB * PLCAP * sizeof(int));
    float*  pval    = (float*)alloc((size_t)BB * PLCAP * sizeof(float));
    float*  rnA     = (float*)alloc(BB * sizeof(float));
    float*  rnB     = (float*)alloc(KMAX * sizeof(float));
    bf16_t* AH      = (bf16_t*)alloc((size_t)BB * DD * sizeof(bf16_t));
    bf16_t* AL      = (bf16_t*)alloc((size_t)BB * DD * sizeof(bf16_t));
    bf16_t* BH      = (bf16_t*)alloc((size_t)KMAX * DD * sizeof(bf16_t));
    bf16_t* BL      = (bf16_t*)alloc((size_t)KMAX * DD * sizeof(bf16_t));
    float*  simc    = (float*)alloc((size_t)BB * KMAX * sizeof(float));

    hipMemsetAsync(zreg, 0, 256 + BB * sizeof(int) + BB * sizeof(float), stream);
    hipMemsetAsync(gkey, 0xFF, 2 * HSZ * sizeof(int), stream);   // keys/vals = -1

    k_fused<<<NB, 256, 0, stream>>>(inputs, pmask, fmem, lmem, targets,
                                    gkey, gval, sc, kctr,
                                    pcnt, pkidx, pval, seAcc, rnA, rnB,
                                    AH, AL, BH, BL, simc, ctr, flag, outp);
}

// Round 12
// 76.413 us; speedup vs baseline: 5.7798x; 5.7798x over previous
//
#include <hip/hip_runtime.h>
#include <math.h>

#define BB 1024        // batch
#define DD 512         // feature dim
#define CC 50000       // classes
#define KMAX 1024      // column space = batch rows (first-occurrence active)
#define PLCAP 32       // per-row positive-list capacity (expected ~2)
#define OVCAP 64       // overflow (lmem-valid unseen) class capacity
#define OVROW 8        // per-row overflow positive capacity
#define SCALE_F 16.0f
#define EPS_F 0.1f

typedef __bf16 bf16_t;
typedef bf16_t bf16x2 __attribute__((ext_vector_type(2)));
typedef bf16_t bf16x8 __attribute__((ext_vector_type(8)));
typedef float f32x4 __attribute__((ext_vector_type(4)));

// =======================================================================
// D1: independent setup work, one item per block.
//  bid <  1024 : row b split (AH/AL) + rnA[b] + rt[b] (first index of target)
//  bid <  2048 : column j = bid-1024: first[j]? class-mean split (BH/BL)+rnB
//  bid >= 2048 : lmem chunk scan -> overflow class list (empty in practice)
// =======================================================================
__global__ __launch_bounds__(256, 4) void k_setup(
        const float* __restrict__ inputs, const float* __restrict__ fmem,
        const int* __restrict__ targets, const int* __restrict__ lmem,
        bf16_t* __restrict__ AH, bf16_t* __restrict__ AL,
        bf16_t* __restrict__ BH, bf16_t* __restrict__ BL,
        float* __restrict__ rnA, float* __restrict__ rnB,
        int* __restrict__ rt, int* __restrict__ afirst,
        int* __restrict__ ovc, int* __restrict__ ovcnt)
{
    __shared__ int tl[BB];
    __shared__ int members[BB];
    __shared__ float red[256];
    __shared__ int mc;
    const int bid = blockIdx.x, tid = threadIdx.x;

    for (int i = tid; i < BB; i += 256) tl[i] = targets[i];
    __syncthreads();

    if (bid < BB) {
        // ---- row path ----
        int b = bid, tgt = tl[b];
        int lmin = 0x7fffffff;
        for (int j = tid; j < BB; j += 256)
            if (tl[j] == tgt && j < lmin) lmin = j;
        members[tid] = lmin;
        __syncthreads();
        for (int s = 128; s > 0; s >>= 1) {
            if (tid < s) members[tid] = min(members[tid], members[tid + s]);
            __syncthreads();
        }
        if (tid == 0) rt[b] = members[0];
        int d0 = tid * 2;
        float a0 = inputs[b * DD + d0];
        float a1 = inputs[b * DD + d0 + 1];
        red[tid] = a0 * a0 + a1 * a1;
        __syncthreads();
        for (int s = 128; s > 0; s >>= 1) {
            if (tid < s) red[tid] += red[tid + s];
            __syncthreads();
        }
        if (tid == 0) rnA[b] = 1.0f / fmaxf(sqrtf(red[0]), 1e-12f);
        bf16_t h0 = (bf16_t)a0, h1 = (bf16_t)a1;
        bf16x2 ph; ph[0] = h0; ph[1] = h1;
        bf16x2 pl; pl[0] = (bf16_t)(a0 - (float)h0); pl[1] = (bf16_t)(a1 - (float)h1);
        *(bf16x2*)(AH + b * DD + d0) = ph;
        *(bf16x2*)(AL + b * DD + d0) = pl;
    } else if (bid < 2 * BB) {
        // ---- column path ----
        int j = bid - BB, tgt = tl[j];
        if (tid == 0) mc = 0;
        __syncthreads();
        int lmin = 0x7fffffff;
        for (int i = tid; i < BB; i += 256)
            if (tl[i] == tgt) { int s = atomicAdd(&mc, 1); members[s] = i; if (i < lmin) lmin = i; }
        red[tid] = (float)lmin;
        __syncthreads();
        for (int s = 128; s > 0; s >>= 1) {
            if (tid < s) red[tid] = fminf(red[tid], red[tid + s]);
            __syncthreads();
        }
        bool first = ((int)red[0] == j);
        int d0 = tid * 2;
        if (!first) {                       // duplicate class: dead column
            bf16x2 z; z[0] = (bf16_t)0.0f; z[1] = (bf16_t)0.0f;
            *(bf16x2*)(BH + j * DD + d0) = z;
            *(bf16x2*)(BL + j * DD + d0) = z;
            if (tid == 0) { rnB[j] = 0.0f; afirst[j] = 0; }
            return;
        }
        int m = mc;
        float b0v = 0.0f, b1v = 0.0f;       // sum members; /count cancels
        for (int i = 0; i < m; ++i) {
            int bb = members[i];
            b0v += inputs[bb * DD + d0];
            b1v += inputs[bb * DD + d0 + 1];
        }
        __syncthreads();
        red[tid] = b0v * b0v + b1v * b1v;
        __syncthreads();
        for (int s = 128; s > 0; s >>= 1) {
            if (tid < s) red[tid] += red[tid + s];
            __syncthreads();
        }
        if (tid == 0) { rnB[j] = 1.0f / fmaxf(sqrtf(red[0]), 1e-12f); afirst[j] = 1; }
        bf16_t g0 = (bf16_t)b0v, g1 = (bf16_t)b1v;
        bf16x2 ph; ph[0] = g0; ph[1] = g1;
        bf16x2 pl; pl[0] = (bf16_t)(b0v - (float)g0); pl[1] = (bf16_t)(b1v - (float)g1);
        *(bf16x2*)(BH + j * DD + d0) = ph;
        *(bf16x2*)(BL + j * DD + d0) = pl;
    } else {
        // ---- lmem overflow scan (lmem is all -1 in this workload) ----
        int c = (bid - 2 * BB) * 256 + tid;
        if (c < CC && lmem[c] != -1) {
            bool seen = false;
            for (int i = 0; i < BB; ++i) if (tl[i] == c) { seen = true; break; }
            if (!seen) { int s = atomicAdd(ovcnt, 1); if (s < OVCAP) ovc[s] = c; }
        }
    }
}

// =======================================================================
// D2: main work.
//  bid <  1024 : gather pm[b][targets[j]] at active columns -> sparse list
//  bid <  2048 : 32x32 MFMA tile (bf16 3-term split) + exp-rowsum epilogue
//  bid >= 2048 : overflow classes (never executes with this data)
// =======================================================================
__global__ __launch_bounds__(256, 4) void k_main(
        const float* __restrict__ pm, const int* __restrict__ targets,
        const int* __restrict__ afirst,
        const bf16_t* __restrict__ AH, const bf16_t* __restrict__ AL,
        const bf16_t* __restrict__ BH, const bf16_t* __restrict__ BL,
        const float* __restrict__ rnA, const float* __restrict__ rnB,
        float* __restrict__ simc, float* __restrict__ seAcc,
        int* __restrict__ pcnt, int* __restrict__ pkidx, float* __restrict__ pval,
        const float* __restrict__ inputs, const float* __restrict__ fmem,
        const int* __restrict__ ovc, const int* __restrict__ ovcnt,
        int* __restrict__ ovrCnt, float* __restrict__ ovS, float* __restrict__ ovV)
{
    __shared__ int tl[BB];
    __shared__ int af[BB];
    __shared__ float red[256];
    const int bid = blockIdx.x, tid = threadIdx.x;

    if (bid < BB) {
        // ---- sparse positive gather (pm row; ~2 nonzeros survive) ----
        for (int i = tid; i < BB; i += 256) { tl[i] = targets[i]; af[i] = afirst[i]; }
        __syncthreads();
        int b = bid;
        const float* __restrict__ row = pm + (size_t)b * CC;
        #pragma unroll
        for (int j = 0; j < 4; ++j) {
            int k = tid + j * 256;
            if (af[k]) {
                float v = row[tl[k]];
                if (v != 0.0f) {
                    int slot = atomicAdd(&pcnt[b], 1);
                    if (slot < PLCAP) {
                        pkidx[b * PLCAP + slot] = k;
                        pval[b * PLCAP + slot] = v;
                    }
                }
            }
        }
    } else if (bid < 2 * BB) {
        // ---- GEMM tile: 4 waves x one 16x16 quadrant ----
        int t = bid - BB;
        float* sem = red;                  // 32 per-row exp partials
        if (tid < 32) sem[tid] = 0.0f;
        __syncthreads();
        int wave = tid >> 6, lane = tid & 63;
        int by = t >> 5, bx = t & 31;
        int b0 = by * 32 + (wave >> 1) * 16;
        int k0 = bx * 32 + (wave & 1) * 16;
        int frow = lane & 15;
        int koff = (lane >> 4) * 8;
        const bf16_t* pAh = AH + (size_t)(b0 + frow) * DD + koff;
        const bf16_t* pAl = AL + (size_t)(b0 + frow) * DD + koff;
        const bf16_t* pBh = BH + (size_t)(k0 + frow) * DD + koff;
        const bf16_t* pBl = BL + (size_t)(k0 + frow) * DD + koff;
        f32x4 acc = {};
        #pragma unroll 2
        for (int dk = 0; dk < DD; dk += 32) {
            bf16x8 ah = *(const bf16x8*)(pAh + dk);
            bf16x8 al = *(const bf16x8*)(pAl + dk);
            bf16x8 bh = *(const bf16x8*)(pBh + dk);
            bf16x8 bl = *(const bf16x8*)(pBl + dk);
            acc = __builtin_amdgcn_mfma_f32_16x16x32_bf16(ah, bh, acc, 0, 0, 0);
            acc = __builtin_amdgcn_mfma_f32_16x16x32_bf16(ah, bl, acc, 0, 0, 0);
            acc = __builtin_amdgcn_mfma_f32_16x16x32_bf16(al, bh, acc, 0, 0, 0);
        }
        // C/D layout: col = lane&15, row = (lane>>4)*4 + reg
        int r4 = (lane >> 4) * 4;
        int col = k0 + (lane & 15);
        float rb = rnB[col];
        int act = afirst[col];
        #pragma unroll
        for (int r = 0; r < 4; ++r) {
            int row = b0 + r4 + r;
            float s = acc[r] * SCALE_F * rnA[row] * rb;
            simc[(size_t)row * KMAX + col] = s;
            float e = act ? expf(s) : 0.0f;
            #pragma unroll
            for (int o = 1; o < 16; o <<= 1) e += __shfl_xor(e, o, 16);
            if ((lane & 15) == 0) atomicAdd(&sem[(wave >> 1) * 16 + r4 + r], e);
        }
        __syncthreads();
        if (tid < 32) atomicAdd(&seAcc[by * 32 + tid], sem[tid]);
    } else {
        // ---- overflow classes (lmem-valid, unseen): generality path ----
        int i = bid - 2 * BB;
        int n = *ovcnt; if (n > OVCAP) n = OVCAP;
        if (i >= n) return;
        int c = ovc[i];
        float nn = 0.0f;
        for (int d = tid; d < DD; d += 256) { float x = fmem[(size_t)c * DD + d]; nn += x * x; }
        red[tid] = nn;
        __syncthreads();
        for (int s = 128; s > 0; s >>= 1) {
            if (tid < s) red[tid] += red[tid + s];
            __syncthreads();
        }
        float rn = 1.0f / fmaxf(sqrtf(red[0]), 1e-12f);
        __syncthreads();
        for (int b = 0; b < BB; ++b) {
            float part = 0.0f;
            for (int d = tid; d < DD; d += 256)
                part += inputs[b * DD + d] * fmem[(size_t)c * DD + d];
            red[tid] = part;
            __syncthreads();
            for (int s = 128; s > 0; s >>= 1) {
                if (tid < s) red[tid] += red[tid + s];
                __syncthreads();
            }
            if (tid == 0) {
                float s = SCALE_F * rnA[b] * rn * red[0];
                atomicAdd(&seAcc[b], expf(s));
                float v = pm[(size_t)b * CC + c];
                if (v != 0.0f) {
                    int s2 = atomicAdd(&ovrCnt[b], 1);
                    if (s2 < OVROW) { ovS[b * OVROW + s2] = s; ovV[b * OVROW + s2] = v; }
                }
            }
            __syncthreads();
        }
    }
}

// =======================================================================
// D3: loss tail — one block, one thread per batch row, LDS reduce.
// =======================================================================
__global__ __launch_bounds__(1024) void k_loss(
        const float* __restrict__ simc, const int* __restrict__ rt,
        const int* __restrict__ pcnt, const int* __restrict__ pkidx,
        const float* __restrict__ pval, const float* __restrict__ seAcc,
        const int* __restrict__ ovrCnt, const float* __restrict__ ovS,
        const float* __restrict__ ovV, float* __restrict__ outp)
{
    __shared__ float red[1024];
    int b = threadIdx.x;
    const float* __restrict__ srow = simc + (size_t)b * KMAX;
    float st = srow[rt[b]];
    int cnt = pcnt[b]; if (cnt > PLCAP) cnt = PLCAP;
    int oc = ovrCnt[b]; if (oc > OVROW) oc = OVROW;
    float sp = 0.0f, spe = 0.0f;
    for (int i = 0; i < cnt; ++i) {
        float v = pval[b * PLCAP + i];
        sp += v;
        spe += v * expf(srow[pkidx[b * PLCAP + i]]);
    }
    for (int i = 0; i < oc; ++i) {
        float v = ovV[b * OVROW + i];
        sp += v;
        spe += v * expf(ovS[b * OVROW + i]);
    }
    float sneg = seAcc[b] - spe;            // sum (1-pm)*exp over valid
    float lb = (1.0f - EPS_F) * (st - logf(sneg + expf(st)));
    float inv = EPS_F / sp;
    for (int i = 0; i < cnt; ++i) {
        float s = srow[pkidx[b * PLCAP + i]];
        lb += inv * pval[b * PLCAP + i] * (s - logf(sneg + expf(s)));
    }
    for (int i = 0; i < oc; ++i) {
        float s = ovS[b * OVROW + i];
        lb += inv * ovV[b * OVROW + i] * (s - logf(sneg + expf(s)));
    }
    red[b] = lb;
    __syncthreads();
    for (int s = 512; s > 0; s >>= 1) {
        if (b < s) red[b] += red[b + s];
        __syncthreads();
    }
    if (b == 0) outp[0] = -red[0] * (1.0f / BB);
}

extern "C" void kernel_launch(void* const* d_in, const int* in_sizes, int n_in,
                              void* d_out, int out_size, void* d_ws, size_t ws_size,
                              hipStream_t stream) {
    const float* inputs  = (const float*)d_in[0];
    const float* pmask   = (const float*)d_in[1];
    const float* fmem    = (const float*)d_in[2];
    const int*   lmem    = (const int*)d_in[3];
    const int*   targets = (const int*)d_in[4];
    float* outp = (float*)d_out;

    char* ws = (char*)d_ws;
    size_t off = 0;
    auto alloc = [&](size_t bytes) -> void* {
        void* p = ws + off;
        off = (off + bytes + 255) & ~(size_t)255;
        return p;
    };
    // zero region (single memset): ovcnt | pcnt | seAcc | ovrCnt
    int*    zreg    = (int*)alloc(256 + 3 * BB * sizeof(int));
    int*    ovcnt   = zreg;
    int*    pcnt    = zreg + 64;
    float*  seAcc   = (float*)(zreg + 64 + BB);
    int*    ovrCnt  = zreg + 64 + 2 * BB;
    size_t  zbytes  = 256 + 3 * BB * sizeof(int);

    int*    rt      = (int*)alloc(BB * sizeof(int));
    int*    afirst  = (int*)alloc(BB * sizeof(int));
    int*    ovc     = (int*)alloc(OVCAP * sizeof(int));
    int*    pkidx   = (int*)alloc((size_t)BB * PLCAP * sizeof(int));
    float*  pval    = (float*)alloc((size_t)BB * PLCAP * sizeof(float));
    float*  ovS     = (float*)alloc((size_t)BB * OVROW * sizeof(float));
    float*  ovV     = (float*)alloc((size_t)BB * OVROW * sizeof(float));
    float*  rnA     = (float*)alloc(BB * sizeof(float));
    float*  rnB     = (float*)alloc(KMAX * sizeof(float));
    bf16_t* AH      = (bf16_t*)alloc((size_t)BB * DD * sizeof(bf16_t));
    bf16_t* AL      = (bf16_t*)alloc((size_t)BB * DD * sizeof(bf16_t));
    bf16_t* BH      = (bf16_t*)alloc((size_t)KMAX * DD * sizeof(bf16_t));
    bf16_t* BL      = (bf16_t*)alloc((size_t)KMAX * DD * sizeof(bf16_t));
    float*  simc    = (float*)alloc((size_t)BB * KMAX * sizeof(float));

    hipMemsetAsync(zreg, 0, zbytes, stream);

    const int NLM = (CC + 255) / 256;                    // 196 lmem blocks
    k_setup<<<2 * BB + NLM, 256, 0, stream>>>(inputs, fmem, targets, lmem,
                                              AH, AL, BH, BL, rnA, rnB,
                                              rt, afirst, ovc, ovcnt);
    k_main<<<2 * BB + OVCAP, 256, 0, stream>>>(pmask, targets, afirst,
                                               AH, AL, BH, BL, rnA, rnB,
                                               simc, seAcc, pcnt, pkidx, pval,
                                               inputs, fmem, ovc, ovcnt,
                                               ovrCnt, ovS, ovV);
    k_loss<<<1, 1024, 0, stream>>>(simc, rt, pcnt, pkidx, pval, seAcc,
                                   ovrCnt, ovS, ovV, outp);
}